// Round 10
// baseline (226.162 us; speedup 1.0000x reference)
//
#include <hip/hip_runtime.h>
#include <hip/hip_bf16.h>
#include <math.h>

// SSD post-processing for MI355X.
// (1) softmax->fg scores [B][7][A] (fp32, materialized); (2) FUSED per-(b,c)
// top-200: lane-privatized 4096-bin LDS hist (R9) + suffix-scan threshold +
// L2-warm collect + bitonic + decode; (3) FUSED per-image NMS (ONE kernel):
// merge-rank sort into LDS -> chunk-by-chunk on-demand IoU mask rows in LDS
// -> wave-0 serial reduce with EARLY EXIT at 200 keeps (prunes BOTH the
// reduce AND the mask IoU work; no global mask traffic; 2 fewer launches).

#define NCLS 8
#define NFG 7
#define TOPK 200
#define NMSM (NFG * TOPK)   // 1400
#define NCH 22              // ceil(1400/64) 64-wide chunks
#define BROWS 64
#define LOW_SCORE 0.01f
#define NMS_THR 0.45f
#define BINS 4096
#define HCOP 4               // lane-privatized hist copies (lane&3)
#define CAP 4096
#define SELTHR 1024          // select block size: 16 waves/CU
#define NMSTHR 1024          // fused NMS block size

// ---------------- stage 1: softmax + transpose ----------------
__global__ __launch_bounds__(256) void score_kernel(
    const float* __restrict__ logits, float* __restrict__ scores, int A, int total) {
  int i = blockIdx.x * 256 + threadIdx.x;   // i = b*A + a
  if (i >= total) return;
  int b = i / A;
  int a = i - b * A;
  const float4* p = (const float4*)(logits + (size_t)i * NCLS);
  float4 v0 = p[0], v1 = p[1];
  float x[NCLS] = {v0.x, v0.y, v0.z, v0.w, v1.x, v1.y, v1.z, v1.w};
  float mx = x[0];
#pragma unroll
  for (int c = 1; c < NCLS; c++) mx = fmaxf(mx, x[c]);
  float e[NCLS];
  float s = 0.0f;
#pragma unroll
  for (int c = 0; c < NCLS; c++) { e[c] = expf(x[c] - mx); s += e[c]; }
  float inv = 1.0f / s;
#pragma unroll
  for (int c = 1; c < NCLS; c++) {
    scores[((size_t)b * NFG + (c - 1)) * A + a] = e[c] * inv;
  }
}

// ---------------- bitonic sort (descending) on shared ulong ----------------
__device__ inline void bitonic_desc(unsigned long long* buf, int P, int tid, int nthr) {
  for (int k = 2; k <= P; k <<= 1) {
    for (int j = k >> 1; j > 0; j >>= 1) {
      __syncthreads();
      for (int i = tid; i < P; i += nthr) {
        int l = i ^ j;
        if (l > i) {
          unsigned long long va = buf[i], vb = buf[l];
          bool descRegion = ((i & k) == 0);
          if (descRegion ? (va < vb) : (va > vb)) { buf[i] = vb; buf[l] = va; }
        }
      }
    }
  }
  __syncthreads();
}

// -------- stage 2 (fused): hist + threshold + collect + sort + decode -------
// One block per (b,c) row. Histogram is 4-way LANE-privatized: copy = lane&3,
// address = bin*4+copy (bounds intra-wave same-address atomic replay — R9).
__global__ __launch_bounds__(SELTHR) void select_kernel(
    const float* __restrict__ scores, const float* __restrict__ deltas,
    const float* __restrict__ dbox, int A,
    float* __restrict__ cboxes, float* __restrict__ cscores) {
  __shared__ unsigned hist[BINS * HCOP];    // 64 KB
  __shared__ unsigned long long buf[CAP];   // 32 KB
  __shared__ int sfx[256];
  __shared__ int s_t, s_cnt;
  int tid = threadIdx.x;
  int row = blockIdx.x;  // b*7 + c
  int b = row / NFG;
  int c = row - b * NFG;
  if (tid == 0) s_cnt = 0;
  for (int i = tid; i < BINS * HCOP; i += SELTHR) hist[i] = 0;
  __syncthreads();

  // pass 1: histogram of the row (float4 loads), lane-privatized atomics
  const float4* p4 = (const float4*)(scores + (size_t)row * A);
  int n4 = A / 4;
  int cp = tid & (HCOP - 1);
  for (int k = tid; k < n4; k += SELTHR) {
    float4 v = p4[k];
    atomicAdd(&hist[((__float_as_uint(v.x) >> 19) << 2) + cp], 1u);
    atomicAdd(&hist[((__float_as_uint(v.y) >> 19) << 2) + cp], 1u);
    atomicAdd(&hist[((__float_as_uint(v.z) >> 19) << 2) + cp], 1u);
    atomicAdd(&hist[((__float_as_uint(v.w) >> 19) << 2) + cp], 1u);
  }
  __syncthreads();

  // per-thread 16-bin sums (uint4 merges the 4 copies), 8-step suffix scan
  const uint4* h4 = (const uint4*)hist;
  if (tid < 256) {
    int s = 0;
#pragma unroll
    for (int k = 0; k < 16; k++) {
      uint4 h = h4[tid * 16 + k];
      s += (int)(h.x + h.y + h.z + h.w);
    }
    sfx[tid] = s;
  }
  __syncthreads();
  for (int off = 1; off < 256; off <<= 1) {
    int v = 0;
    if (tid < 256) v = sfx[tid] + ((tid + off < 256) ? sfx[tid + off] : 0);
    __syncthreads();
    if (tid < 256) sfx[tid] = v;
    __syncthreads();
  }
  if (tid < 256) {
    if (sfx[0] < TOPK) {
      if (tid == 0) s_t = 0;
    } else {
      bool mine = (sfx[tid] >= TOPK) && (tid == 255 || sfx[tid + 1] < TOPK);
      if (mine) {
        int cum = (tid == 255) ? 0 : sfx[tid + 1];
        int t = tid * 16 + 15;
        for (; t >= tid * 16; t--) {
          uint4 h = h4[t];
          cum += (int)(h.x + h.y + h.z + h.w);
          if (cum >= TOPK) break;
        }
        s_t = t;
      }
    }
  }
  __syncthreads();

  // pass 2: collect candidates (bin >= threshold); reads hit L2
  unsigned tbin = (unsigned)s_t;
  for (int k = tid; k < n4; k += SELTHR) {
    float4 v = p4[k];
    float c4[4] = {v.x, v.y, v.z, v.w};
#pragma unroll
    for (int j = 0; j < 4; j++) {
      unsigned key = __float_as_uint(c4[j]);
      if ((key >> 19) >= tbin) {
        int pos = atomicAdd(&s_cnt, 1);
        if (pos < CAP)
          buf[pos] = ((unsigned long long)key << 32) | (unsigned)(~(4 * k + j));
      }
    }
  }
  __syncthreads();
  int cnt = s_cnt; if (cnt > CAP) cnt = CAP;
  int P = 256; while (P < cnt) P <<= 1;
  for (int i = cnt + tid; i < P; i += SELTHR) buf[i] = 0ull;
  __syncthreads();
  bitonic_desc(buf, P, tid, SELTHR);

  // epilogue: decode the top-200 directly
  if (tid < TOPK) {
    unsigned long long v = buf[tid];
    float sc = __uint_as_float((unsigned)(v >> 32));
    int a = (int)(~(unsigned)(v & 0xFFFFFFFFull));
    a = a < 0 ? 0 : (a >= A ? A - 1 : a);   // pad-entry safety (score==0 there)
    const float* db = dbox + (size_t)a * 4;
    float w = db[2] - db[0];
    float h = db[3] - db[1];
    float cx = db[0] + 0.5f * w;
    float cy = db[1] + 0.5f * h;
    const float* dd = deltas + ((size_t)b * A + a) * 4;
    float pcx = dd[0] / 10.0f * w + cx;
    float pcy = dd[1] / 10.0f * h + cy;
    float pw = expf(dd[2] / 5.0f) * w;
    float ph = expf(dd[3] / 5.0f) * h;
    float x0 = fminf(fmaxf(pcx - 0.5f * pw, 0.0f), 1.0f);
    float y0 = fminf(fmaxf(pcy - 0.5f * ph, 0.0f), 1.0f);
    float x1 = fminf(fmaxf(pcx + 0.5f * pw, 0.0f), 1.0f);
    float y1 = fminf(fmaxf(pcy + 0.5f * ph, 0.0f), 1.0f);
    size_t m = (size_t)b * NMSM + (size_t)c * TOPK + tid;
    float* cb = cboxes + m * 4;
    cb[0] = x0; cb[1] = y0; cb[2] = x1; cb[3] = y1;
    cscores[m] = sc;
  }
}

// ---------------- stage 3 (fused NMS): sort + on-demand mask + reduce -------
// One block per image, 1024 threads. Everything in LDS (~56 KB):
//   merge-rank sort (7 binary searches, as before) -> ssx0..ssar/ssord;
//   per chunk bi: all threads compute the 64x(22-bi) mask words for chunk
//   bi's rows into rowm (IoU vs LDS broadcasts), then wave 0 runs the serial
//   reduce step; EARLY EXIT at 200 keeps prunes both reduce AND mask work.
__global__ __launch_bounds__(NMSTHR) void nms_kernel(
    const float* __restrict__ cboxes, const float* __restrict__ cscores,
    float* __restrict__ out, int B) {
  __shared__ unsigned long long keys[NMSM];              // 11.2 KB
  __shared__ float ssx0[NMSM], ssy0[NMSM], ssx1[NMSM], ssy1[NMSM], ssar[NMSM];
  __shared__ int ssord[NMSM];                            // 28 + 5.6 KB
  __shared__ unsigned long long rowm[BROWS * NCH];       // 11.3 KB
  __shared__ unsigned long long skeep[NCH];
  __shared__ int spfx[NCH];
  __shared__ int s_cnt, s_done;
  int tid = threadIdx.x;
  int b = blockIdx.x;
  size_t base = (size_t)b * NMSM;

  // ---- merge-rank sort into LDS ----
  const float* sc = cscores + base;
  if (tid == 0) { s_cnt = 0; s_done = 0; }
  __syncthreads();
  int myv = 0;
  for (int m = tid; m < NMSM; m += NMSTHR) {
    float s = sc[m];
    unsigned k32 = (s > LOW_SCORE) ? __float_as_uint(s) : 0u;
    if (k32) myv++;
    keys[m] = ((unsigned long long)k32 << 32) | (unsigned)(~m);
  }
  if (myv) atomicAdd(&s_cnt, myv);
  __syncthreads();

  for (int m = tid; m < NMSM; m += NMSTHR) {
    unsigned long long k = keys[m];
    int c = m / TOPK;
    int lo[NFG], hi[NFG];
#pragma unroll
    for (int cc = 0; cc < NFG; cc++) { lo[cc] = 0; hi[cc] = TOPK; }
#pragma unroll
    for (int s8 = 0; s8 < 8; s8++) {
#pragma unroll
      for (int cc = 0; cc < NFG; cc++) {
        if (lo[cc] < hi[cc]) {
          int mid = (lo[cc] + hi[cc]) >> 1;
          if (keys[cc * TOPK + mid] > k) lo[cc] = mid + 1; else hi[cc] = mid;
        }
      }
    }
    int p = 0;
#pragma unroll
    for (int cc = 0; cc < NFG; cc++) p += lo[cc];

    const float* cb = cboxes + (base + m) * 4;
    float off = 4.0f * (float)(c + 1);
    float x0 = cb[0] + off, y0 = cb[1] + off, x1 = cb[2] + off, y1 = cb[3] + off;
    ssord[p] = m;
    ssx0[p] = x0; ssy0[p] = y0;
    ssx1[p] = x1; ssy1[p] = y1;
    ssar[p] = (x1 - x0) * (y1 - y0);
  }
  __syncthreads();

  // ---- chunked suppress: alive word per lane (wave 0), on-demand mask ----
  int nvalid = s_cnt;
  unsigned long long remove = 0ull;
  int kept = 0, processed = 0;
  bool act = (tid < NCH);
  int li = act ? tid : 0;
  if (act) {
    int base64 = tid * 64;
    if (base64 + 64 <= nvalid) remove = ~0ull;
    else if (base64 < nvalid) remove = (~0ull) >> (64 - (nvalid - base64));
  }

  for (int bi = 0; bi < NCH; bi++) {
    // mask rows for chunk bi vs chunks cj >= bi (all 1024 threads).
    // Wave-uniform cj (t>>6), per-lane row i (t&63): j-reads broadcast.
    int nt = 64 * (NCH - bi);
    for (int t = tid; t < nt; t += NMSTHR) {
      int il = t & 63;
      int cj = bi + (t >> 6);
      int i = bi * 64 + il;
      unsigned long long bits = 0ull;
      if (i < NMSM) {
        float x0 = ssx0[i], y0 = ssy0[i];
        float x1 = ssx1[i], y1 = ssy1[i], a = ssar[i];
        int jbase = cj * 64;
#pragma unroll 8
        for (int jj = 0; jj < 64; jj++) {
          int jg = jbase + jj;
          if (jg < NMSM) {
            float xl = fmaxf(x0, ssx0[jg]);
            float yt = fmaxf(y0, ssy0[jg]);
            float xr = fminf(x1, ssx1[jg]);
            float yb = fminf(y1, ssy1[jg]);
            float inter = fmaxf(xr - xl, 0.0f) * fmaxf(yb - yt, 0.0f);
            float iou = inter / (a + ssar[jg] - inter);
            if (jg > i && iou > NMS_THR) bits |= 1ull << jj;
          }
        }
      }
      rowm[il * NCH + cj] = bits;
    }
    __syncthreads();

    // wave 0: serial reduce for chunk bi (identical structure to the proven
    // nms_serial inner loop; rows now come from LDS — addresses static, so
    // the compiler preloads them ahead of the dependent AND chain)
    if (tid < 64) {
      unsigned long long cur = __shfl(remove, bi);
      unsigned long long wmask = (act && tid >= bi) ? ~0ull : 0ull;
#pragma unroll 8
      for (int d = 0; d < 64; d++) {
        unsigned long long rowd  = rowm[d * NCH + li];   // per-lane word
        unsigned long long diagd = rowm[d * NCH + bi];   // broadcast
        bool kd = (cur >> d) & 1ull;                     // uniform value
        cur    &= ~(kd ? diagd : 0ull);
        remove &= ~(kd ? (rowd & wmask) : 0ull);
      }
      remove = (tid == bi) ? cur : remove;
      kept += (int)__popcll(cur);       // cur uniform across wave 0
      processed = bi + 1;
      if (tid == 0 && (kept >= TOPK || bi == NCH - 1)) s_done = 1;
    }
    __syncthreads();
    if (s_done) break;   // uniform decision; later ranks provably >= 200
  }

  // unprocessed chunks: rank >= kept >= 200 -> zero their keep words
  if (act) skeep[tid] = (tid < processed) ? remove : 0ull;
  __syncthreads();
  if (tid == 0) {
    int s = 0;
    for (int w = 0; w < NCH; w++) { spfx[w] = s; s += __popcll(skeep[w]); }
  }
  __syncthreads();

  // ---- output ----
  float* ob = out + (size_t)b * TOPK * 4;
  float* os = out + (size_t)B * TOPK * 4 + (size_t)b * TOPK;
  float* ol = out + (size_t)B * TOPK * 5 + (size_t)b * TOPK;
  for (int r = tid; r < TOPK; r += NMSTHR) {
    ob[r * 4 + 0] = 0.0f; ob[r * 4 + 1] = 0.0f;
    ob[r * 4 + 2] = 0.0f; ob[r * 4 + 3] = 0.0f;
    os[r] = 0.0f; ol[r] = 0.0f;
  }
  __syncthreads();
  for (int i = tid; i < NMSM; i += NMSTHR) {
    int w = i >> 6;
    unsigned long long kw = skeep[w];
    if ((kw >> (i & 63)) & 1ull) {
      int r = spfx[w] + __popcll(kw & ((1ull << (i & 63)) - 1ull));
      if (r < TOPK) {
        int m = ssord[i];
        const float* cb = cboxes + (base + m) * 4;
        ob[r * 4 + 0] = cb[0]; ob[r * 4 + 1] = cb[1];
        ob[r * 4 + 2] = cb[2]; ob[r * 4 + 3] = cb[3];
        os[r] = cscores[base + m];
        ol[r] = (float)(m / TOPK + 1);
      }
    }
  }
}

extern "C" void kernel_launch(void* const* d_in, const int* in_sizes, int n_in,
                              void* d_out, int out_size, void* d_ws, size_t ws_size,
                              hipStream_t stream) {
  const float* logits = (const float*)d_in[0];
  const float* deltas = (const float*)d_in[1];
  const float* dbox   = (const float*)d_in[2];
  int A = in_sizes[2] / 4;
  int B = in_sizes[0] / (A * NCLS);
  int NROWS = B * NFG;
  float* out = (float*)d_out;

  // workspace layout (mask + sorted arrays eliminated by the fused NMS)
  float* scores_ws = (float*)d_ws;                                  // B*7*A floats
  float* cboxes = scores_ws + (size_t)B * NFG * A;                  // B*1400*4
  float* cscores = cboxes + (size_t)B * NMSM * 4;                   // B*1400

  int total = B * A;
  score_kernel<<<(total + 255) / 256, 256, 0, stream>>>(logits, scores_ws, A, total);
  select_kernel<<<NROWS, SELTHR, 0, stream>>>(scores_ws, deltas, dbox, A,
                                              cboxes, cscores);
  nms_kernel<<<B, NMSTHR, 0, stream>>>(cboxes, cscores, out, B);
}